// Round 11
// baseline (315.388 us; speedup 1.0000x reference)
//
#include <hip/hip_runtime.h>

typedef unsigned short u16;
typedef __attribute__((ext_vector_type(8))) short bf16x8;
typedef __attribute__((ext_vector_type(4))) float f32x4;

#define SEQ 4096
#define DIM 1024

// ---------- bf16 helpers (OCP bf16 = top 16 bits of fp32, RNE) ----------
__device__ __forceinline__ u16 f2bf(float f) {
  unsigned u = __float_as_uint(f);
  return (u16)((u + 0x7fffu + ((u >> 16) & 1u)) >> 16);
}
__device__ __forceinline__ float bf2f(u16 h) {
  return __uint_as_float(((unsigned)h) << 16);
}

// ---------- async global->LDS, 16B per lane ----------
__device__ __forceinline__ void gload_lds16(const void* g, void* l) {
  __builtin_amdgcn_global_load_lds(
      (const __attribute__((address_space(1))) void*)g,
      (__attribute__((address_space(3))) void*)l, 16, 0, 0);
}

// counted-vmcnt discipline (T4): literals only, "memory" clobber fences compiler
#define VM0 asm volatile("s_waitcnt vmcnt(0)" ::: "memory")
#define VM4 asm volatile("s_waitcnt vmcnt(4)" ::: "memory")
#define VM8 asm volatile("s_waitcnt vmcnt(8)" ::: "memory")
#define BAR __builtin_amdgcn_s_barrier()

// ---------- tile-packed operand layout (r4/r7-verified: 0 bank conflicts) ----------
// Matrix [R][Kd] stored as 128x32 tiles; tile (rb,kb) at (rb*(Kd/32)+kb)*4096.
// Within tile, 16B slot s = ((r7>>4)<<6) | ((c5>>3)<<4) | (r7&15), elem = c5&7.
__device__ __forceinline__ size_t pkoff(int row, int col, int kd) {
  int tile = (row >> 7) * (kd >> 5) + (col >> 5);
  int r7 = row & 127, c5 = col & 31;
  int slot = ((r7 >> 4) << 6) | ((c5 >> 3) << 4) | (r7 & 15);
  return (size_t)tile * 4096 + (size_t)(slot * 8 + (c5 & 7));
}

// stage a 2-tile quarter (256 rows x 32 K) with 512 threads: 2 gloads/thread
__device__ __forceinline__ void stage_q512(const u16* __restrict__ g,
                                           int kb, int nkb, u16* ldsq, int tid) {
  const int w = tid >> 6;  // 0..7
  gload_lds16(g + (size_t)kb * 4096 + tid * 8, ldsq + w * 512);
  gload_lds16(g + ((size_t)nkb + kb) * 4096 + tid * 8, ldsq + 4096 + w * 512);
}

// ---------- 256^2-tile 3-pair NT GEMM core, counted-vmcnt, 2-barrier ----------
// r3/r4/r6-verified; r10 verdict: r9 read-ahead was NULL (86.8->86.9, +24
// VGPR) -> reverted to this r8 body. Three schedule variants all land
// 86.4-88.2us on s_kernel: this template is PLATEAUED; no more schedule
// surgery without disasm evidence. MFMA-bound model: floor 103GF/2075TF=50us.
// 3-pair split is numerically REQUIRED (softmax logit std ~O(300)).
__device__ __forceinline__ void gemm3_256(
    const u16* __restrict__ A0, const u16* __restrict__ A1,
    const u16* __restrict__ B0, const u16* __restrict__ B1,
    int nkb, u16* lds, f32x4 (&acc)[8][4]) {
  const int tid = threadIdx.x;       // 0..511
  const int w = tid >> 6, l = tid & 63;
  const int wm = w >> 2, wn = w & 3;

#pragma unroll
  for (int mi = 0; mi < 8; ++mi)
#pragma unroll
    for (int ni = 0; ni < 4; ++ni)
      acc[mi][ni] = (f32x4){0.f, 0.f, 0.f, 0.f};

  // quarter bases within a 32768-u16 buffer
  const int QA0 = 0, QA1 = 8192, QB0 = 16384, QB1 = 24576;
  const int aoff = wm * 4096 + l * 8;                       // + mi*512
  const int boff = ((wn & 2) >> 1) * 4096 + (wn & 1) * 2048 + l * 8;  // + ni*512

  // prologue: step 0, strict quarter order A0,B0 | B1,A1 (8 gloads)
  stage_q512(A0, 0, nkb, lds + QA0, tid);
  stage_q512(B0, 0, nkb, lds + QB0, tid);
  stage_q512(B1, 0, nkb, lds + QB1, tid);
  stage_q512(A1, 0, nkb, lds + QA1, tid);

  for (int kb = 0; kb < nkb; ++kb) {
    u16* cur = lds + (kb & 1) * 32768;
    u16* nxt = lds + ((kb + 1) & 1) * 32768;
    const bool pf = (kb + 1 < nkb);
    bf16x8 a0[8], b0[4];

    // ---- entry: A0,B0 of kb valid for all waves
    VM4;
    BAR;
    if (pf) {
      stage_q512(A0, kb + 1, nkb, nxt + QA0, tid);
      stage_q512(B0, kb + 1, nkb, nxt + QB0, tid);
    }
#pragma unroll
    for (int i = 0; i < 8; ++i) a0[i] = *(const bf16x8*)(cur + QA0 + aoff + i * 512);
#pragma unroll
    for (int i = 0; i < 4; ++i) b0[i] = *(const bf16x8*)(cur + QB0 + boff + i * 512);
    __builtin_amdgcn_s_setprio(1);
#pragma unroll
    for (int mi = 0; mi < 8; ++mi)
#pragma unroll
      for (int ni = 0; ni < 4; ++ni)
        acc[mi][ni] = __builtin_amdgcn_mfma_f32_16x16x32_bf16(
            a0[mi], b0[ni], acc[mi][ni], 0, 0, 0);
    __builtin_amdgcn_s_setprio(0);

    // ---- mid: B1,A1 of kb valid for all waves; then P1+P2 barrier-free
    if (pf) { VM4; } else { VM0; }
    BAR;
    if (pf) {
      stage_q512(B1, kb + 1, nkb, nxt + QB1, tid);
      stage_q512(A1, kb + 1, nkb, nxt + QA1, tid);
    }
    {
      bf16x8 b1[4];
#pragma unroll
      for (int i = 0; i < 4; ++i) b1[i] = *(const bf16x8*)(cur + QB1 + boff + i * 512);
      __builtin_amdgcn_s_setprio(1);
#pragma unroll
      for (int mi = 0; mi < 8; ++mi)
#pragma unroll
        for (int ni = 0; ni < 4; ++ni)
          acc[mi][ni] = __builtin_amdgcn_mfma_f32_16x16x32_bf16(
              a0[mi], b1[ni], acc[mi][ni], 0, 0, 0);
      __builtin_amdgcn_s_setprio(0);
    }
    {
      bf16x8 a1[8];
#pragma unroll
      for (int i = 0; i < 8; ++i) a1[i] = *(const bf16x8*)(cur + QA1 + aoff + i * 512);
      __builtin_amdgcn_s_setprio(1);
#pragma unroll
      for (int mi = 0; mi < 8; ++mi)
#pragma unroll
        for (int ni = 0; ni < 4; ++ni)
          acc[mi][ni] = __builtin_amdgcn_mfma_f32_16x16x32_bf16(
              a1[mi], b0[ni], acc[mi][ni], 0, 0, 0);
      __builtin_amdgcn_s_setprio(0);
    }
  }
  __syncthreads();
}

// ---------- 256^2-tile single-pair NT GEMM core, counted-vmcnt ----------
// HW-VERIFIED (r4, qkv z=2). 4 rotating 32KB bufs, depth-3 prefetch,
// vmcnt(8) steady / 4 / 0 tail.
__device__ __forceinline__ void gemm1_256(
    const u16* __restrict__ A, const u16* __restrict__ B,
    int nkb, u16* lds, f32x4 (&acc)[8][4]) {
  const int tid = threadIdx.x;
  const int w = tid >> 6, l = tid & 63;
  const int wm = w >> 2, wn = w & 3;

#pragma unroll
  for (int mi = 0; mi < 8; ++mi)
#pragma unroll
    for (int ni = 0; ni < 4; ++ni)
      acc[mi][ni] = (f32x4){0.f, 0.f, 0.f, 0.f};

  const int aoff = wm * 4096 + l * 8;
  const int boff = ((wn & 2) >> 1) * 4096 + (wn & 1) * 2048 + l * 8;

  stage_q512(A, 0, nkb, lds + 0 * 16384, tid);
  stage_q512(B, 0, nkb, lds + 0 * 16384 + 8192, tid);
  stage_q512(A, 1, nkb, lds + 1 * 16384, tid);
  stage_q512(B, 1, nkb, lds + 1 * 16384 + 8192, tid);
  stage_q512(A, 2, nkb, lds + 2 * 16384, tid);
  stage_q512(B, 2, nkb, lds + 2 * 16384 + 8192, tid);

  for (int kb = 0; kb < nkb; ++kb) {
    if (kb + 2 < nkb) { VM8; } else if (kb + 1 < nkb) { VM4; } else { VM0; }
    BAR;
    if (kb + 3 < nkb) {
      u16* nb = lds + ((kb + 3) & 3) * 16384;
      stage_q512(A, kb + 3, nkb, nb, tid);
      stage_q512(B, kb + 3, nkb, nb + 8192, tid);
    }
    const u16* cb = lds + (kb & 3) * 16384;
    bf16x8 av[8], bv[4];
#pragma unroll
    for (int i = 0; i < 8; ++i) av[i] = *(const bf16x8*)(cb + aoff + i * 512);
#pragma unroll
    for (int i = 0; i < 4; ++i) bv[i] = *(const bf16x8*)(cb + 8192 + boff + i * 512);
    __builtin_amdgcn_s_setprio(1);
#pragma unroll
    for (int mi = 0; mi < 8; ++mi)
#pragma unroll
      for (int ni = 0; ni < 4; ++ni)
        acc[mi][ni] = __builtin_amdgcn_mfma_f32_16x16x32_bf16(
            av[mi], bv[ni], acc[mi][ni], 0, 0, 0);
    __builtin_amdgcn_s_setprio(0);
  }
  __syncthreads();
}

// ---------- 512-thr epilogue: 256^2 C regs -> packed bf16 h/l via LDS ----------
// template<HASL> specialization (r8): no runtime if(L) in the VT instantiation.
template <bool HASL>
__device__ __forceinline__ void epilogue_pack256(
    f32x4 (&acc)[8][4], u16* lds, int row0, int col0, int kd,
    u16* __restrict__ H, u16* __restrict__ L) {
  const int tid = threadIdx.x, w = tid >> 6, l = tid & 63;
  const int wm = w >> 2, wn = w & 3, lr = l & 15, q = l >> 4;
  float* lC = (float*)lds;
#pragma unroll
  for (int p = 0; p < 4; ++p) {
    if (wm == (p >> 1)) {
      const int mib = (p & 1) * 4;
#pragma unroll
      for (int mi2 = 0; mi2 < 4; ++mi2)
#pragma unroll
        for (int ni = 0; ni < 4; ++ni)
#pragma unroll
          for (int r = 0; r < 4; ++r)
            lC[(mi2 * 16 + q * 4 + r) * 260 + wn * 64 + ni * 16 + lr] =
                acc[mib + mi2][ni][r];
    }
    __syncthreads();
#pragma unroll
    for (int j = 0; j < 2; ++j) {
      int u = tid + 512 * j;
      int row = u >> 4, c0 = (u & 15) * 16;
      u16 hbuf[16], lbuf[16];
#pragma unroll
      for (int i = 0; i < 16; ++i) {
        float v = lC[row * 260 + c0 + i];
        u16 hv = f2bf(v);
        hbuf[i] = hv;
        if (HASL) lbuf[i] = f2bf(v - bf2f(hv));
      }
      int rg = row0 + p * 64 + row;
      size_t o0 = pkoff(rg, col0 + c0, kd);
      size_t o1 = pkoff(rg, col0 + c0 + 8, kd);
      *(bf16x8*)(H + o0) = *(bf16x8*)(hbuf);
      *(bf16x8*)(H + o1) = *(bf16x8*)(hbuf + 8);
      if (HASL) {
        *(bf16x8*)(L + o0) = *(bf16x8*)(lbuf);
        *(bf16x8*)(L + o1) = *(bf16x8*)(lbuf + 8);
      }
    }
    if (p < 3) __syncthreads();
  }
}

// ---------- 512-thr fused local-softmax epilogue (r11) ----------
// Same proven 4-pass LDS-repack skeleton as pack256, but instead of h/l
// split: per 64-row pass, 16 threads/row reduce max+expsum over the block's
// 256 cols (width-16 shfl), write P' = exp(s*scale - m_local) bf16
// tile-packed, plus aux (m_local, expsum) per (row, chunk=block X).
// Two-level softmax: o_kernel combines chunks via beta = exp(m_c-gmax)/gsum.
__device__ __forceinline__ void epilogue_softmax256(
    f32x4 (&acc)[8][4], u16* lds, int row0, int col0, int chunk,
    u16* __restrict__ P, float* __restrict__ AuxM, float* __restrict__ AuxS) {
  const int tid = threadIdx.x, w = tid >> 6, l = tid & 63;
  const int wm = w >> 2, wn = w & 3, lr = l & 15, q = l >> 4;
  const float scale = 0.03125f;  // 1/sqrt(1024)
  float* lC = (float*)lds;
#pragma unroll
  for (int p = 0; p < 4; ++p) {
    if (wm == (p >> 1)) {
      const int mib = (p & 1) * 4;
#pragma unroll
      for (int mi2 = 0; mi2 < 4; ++mi2)
#pragma unroll
        for (int ni = 0; ni < 4; ++ni)
#pragma unroll
          for (int r = 0; r < 4; ++r)
            lC[(mi2 * 16 + q * 4 + r) * 260 + wn * 64 + ni * 16 + lr] =
                acc[mib + mi2][ni][r] * scale;
    }
    __syncthreads();
#pragma unroll
    for (int j = 0; j < 2; ++j) {
      int u = tid + 512 * j;
      int row = u >> 4, c0 = (u & 15) * 16;
      float v[16];
      float mx = -3.4e38f;
#pragma unroll
      for (int i = 0; i < 16; ++i) {
        v[i] = lC[row * 260 + c0 + i];
        mx = fmaxf(mx, v[i]);
      }
#pragma unroll
      for (int off = 8; off; off >>= 1) mx = fmaxf(mx, __shfl_xor(mx, off, 16));
      float sum = 0.f;
#pragma unroll
      for (int i = 0; i < 16; ++i) {
        v[i] = __expf(v[i] - mx);
        sum += v[i];
      }
#pragma unroll
      for (int off = 8; off; off >>= 1) sum += __shfl_xor(sum, off, 16);
      u16 pb[16];
#pragma unroll
      for (int i = 0; i < 16; ++i) pb[i] = f2bf(v[i]);
      int rg = row0 + p * 64 + row;
      *(bf16x8*)(P + pkoff(rg, col0 + c0, SEQ)) = *(bf16x8*)(pb);
      *(bf16x8*)(P + pkoff(rg, col0 + c0 + 8, SEQ)) = *(bf16x8*)(pb + 8);
      if ((u & 15) == 0) {
        AuxM[(size_t)rg * 16 + chunk] = mx;
        AuxS[(size_t)rg * 16 + chunk] = sum;
      }
    }
    if (p < 3) __syncthreads();
  }
}

// ---------- kernels ----------

__global__ __launch_bounds__(256) void prep_kernel(
    const float* __restrict__ X,
    const float* __restrict__ W0, const float* __restrict__ W1, const float* __restrict__ W2,
    u16* __restrict__ Xh, u16* __restrict__ Xl,
    u16* __restrict__ H0, u16* __restrict__ L0,
    u16* __restrict__ H1, u16* __restrict__ L1,
    u16* __restrict__ H2) {
  const int z = blockIdx.z;
  const int tx = threadIdx.x, ty = threadIdx.y;
  if (z == 0) {
    int idx = (blockIdx.y * 32 + blockIdx.x) * 256 + ty * 32 + tx;
    int row = idx >> 6;
    int c0 = (idx & 63) * 16;
    u16 h[16], lo[16];
#pragma unroll
    for (int j = 0; j < 4; ++j) {
      float4 x = *(const float4*)(X + (size_t)row * DIM + c0 + j * 4);
      float v;
      v = x.x; h[j*4+0] = f2bf(v); lo[j*4+0] = f2bf(v - bf2f(h[j*4+0]));
      v = x.y; h[j*4+1] = f2bf(v); lo[j*4+1] = f2bf(v - bf2f(h[j*4+1]));
      v = x.z; h[j*4+2] = f2bf(v); lo[j*4+2] = f2bf(v - bf2f(h[j*4+2]));
      v = x.w; h[j*4+3] = f2bf(v); lo[j*4+3] = f2bf(v - bf2f(h[j*4+3]));
    }
    size_t o0 = pkoff(row, c0, DIM);
    size_t o1 = pkoff(row, c0 + 8, DIM);
    *(bf16x8*)(Xh + o0) = *(bf16x8*)(h);
    *(bf16x8*)(Xl + o0) = *(bf16x8*)(lo);
    *(bf16x8*)(Xh + o1) = *(bf16x8*)(h + 8);
    *(bf16x8*)(Xl + o1) = *(bf16x8*)(lo + 8);
    return;
  }
  __shared__ float t[32][33];
  const float* W = (z == 1) ? W0 : (z == 2) ? W1 : W2;
  u16* H = (z == 1) ? H0 : (z == 2) ? H1 : H2;
  u16* L = (z == 1) ? L0 : (z == 2) ? L1 : nullptr;
  const int i0 = blockIdx.y * 32, o0 = blockIdx.x * 32;
#pragma unroll
  for (int m = 0; m < 4; ++m)
    t[ty + 8 * m][tx] = W[(size_t)(i0 + ty + 8 * m) * DIM + o0 + tx];
  __syncthreads();
#pragma unroll
  for (int m = 0; m < 4; ++m) {
    float v = t[tx][ty + 8 * m];
    u16 h = f2bf(v);
    size_t o = pkoff(o0 + ty + 8 * m, i0 + tx, DIM);
    H[o] = h;
    if (L) L[o] = f2bf(v - bf2f(h));
  }
}

// qkv on the 256^2 counted-vmcnt cores. Grid 4x16x3, 512 thr, T1 swizzle.
__global__ __launch_bounds__(512, 2) void qkv_kernel(
    const u16* __restrict__ Xh, const u16* __restrict__ Xl,
    const u16* __restrict__ Wh0, const u16* __restrict__ Wl0,
    const u16* __restrict__ Wh1, const u16* __restrict__ Wl1,
    const u16* __restrict__ Wh2,
    u16* __restrict__ Qh, u16* __restrict__ Ql,
    u16* __restrict__ Kh, u16* __restrict__ Kl,
    u16* __restrict__ VT) {
  __shared__ __align__(16) u16 lds[2 * 32768];  // 128 KB
  const int z = blockIdx.z;
  const int bid = blockIdx.y * 4 + blockIdx.x;  // [0,64)
  const int xcd = bid & 7, c = bid >> 3;        // c in [0,8)
  const int Y = xcd * 2 + (c >> 2);             // [0,16) over SEQ panels
  const int Xp = c & 3;                         // [0,4)  over DIM panels
  f32x4 acc[8][4];
  if (z < 2) {
    const u16* Wh = z ? Wh1 : Wh0;
    const u16* Wl = z ? Wl1 : Wl0;
    const int row0 = Y * 256;   // over SEQ
    const int col0 = Xp * 256;  // over DIM
    gemm3_256(Xh + (size_t)row0 * DIM, Xl + (size_t)row0 * DIM,
              Wh + (size_t)col0 * DIM, Wl + (size_t)col0 * DIM,
              DIM / 32, lds, acc);
    epilogue_pack256<true>(acc, lds, row0, col0, DIM, z ? Kh : Qh, z ? Kl : Ql);
  } else {
    const int row0 = Xp * 256;  // over DIM
    const int col0 = Y * 256;   // over SEQ
    gemm1_256(Wh2 + (size_t)row0 * DIM, Xh + (size_t)col0 * DIM,
              DIM / 32, lds, acc);
    epilogue_pack256<false>(acc, lds, row0, col0, SEQ, VT, nullptr);
  }
}

// s_kernel (r11): QK^T * 1/32 -> FUSED local softmax -> P' bf16 packed + aux.
// Replaces the S fp32 64MB round-trip + separate softmax kernel entirely.
// P' = exp(s - m_local(block 256 cols)); aux[(row,chunk)] = (m_local, expsum).
__global__ __launch_bounds__(512, 2) void s_kernel(
    const u16* __restrict__ Qh, const u16* __restrict__ Ql,
    const u16* __restrict__ Kh, const u16* __restrict__ Kl,
    u16* __restrict__ P, float* __restrict__ AuxM, float* __restrict__ AuxS) {
  __shared__ __align__(16) u16 lds[2 * 32768];  // 128 KB
  const int bid = blockIdx.y * 16 + blockIdx.x;  // [0,256)
  const int xcd = bid & 7, c = bid >> 3;         // c in [0,32)
  const int Y = (xcd & 3) * 4 + (c >> 3);        // [0,16)
  const int X = (xcd >> 2) * 8 + (c & 7);        // [0,16)
  const int row0 = Y * 256, col0 = X * 256;
  f32x4 acc[8][4];
  gemm3_256(Qh + (size_t)row0 * DIM, Ql + (size_t)row0 * DIM,
            Kh + (size_t)col0 * DIM, Kl + (size_t)col0 * DIM,
            DIM / 32, lds, acc);
  epilogue_softmax256(acc, lds, row0, col0, X, P, AuxM, AuxS);
}

// ---------- o-only code at module end (r8 codegen isolation) ----------

// stage one packed 128x32 tile (4096 elems, contiguous) into LDS (256 thr)
__device__ __forceinline__ void stage_tile_pk(const u16* __restrict__ g,
                                              u16* lds, int tid) {
  const int w = tid >> 6;
  gload_lds16(g + (size_t)tid * 8, lds + (size_t)(w * 64) * 8);
  gload_lds16(g + (size_t)(256 + tid) * 8, lds + (size_t)(256 + w * 64) * 8);
}

// O = softmax(S) @ V via two-level combine (r11): per-row beta_c =
// exp(m_c - gmax)/gsum (clamped >=1e-15); flash-style running rescale
// acc *= beta_{c-1}/beta_c at each 8-kb (256-key) chunk boundary, final
// acc *= beta_15. Exact algebra: O = sum_c beta_c (P'_c @ V_c). Pipeline =
// r7-verified counted-vmcnt 128^2 core (4 rotating 16KB bufs, depth-3,
// VM8/4/0). Grid 256 = 1 block/CU; (256,1) allows full VGPR, no spill.
__global__ __launch_bounds__(256, 1) void o_kernel(
    const u16* __restrict__ P, const u16* __restrict__ VT,
    const float* __restrict__ AuxM, const float* __restrict__ AuxS,
    float* __restrict__ O) {
  __shared__ __align__(16) u16 lds[4 * 8192];  // 64 KB pipeline
  __shared__ float rt[128][17];  // [r][c>=1]=ratio into chunk c; [r][0]=final
  const int bid = blockIdx.y * 8 + blockIdx.x;  // [0,256)
  const int xcd = bid & 7, c = bid >> 3;
  const int Y = xcd * 4 + (c >> 3);  // [0,32) over SEQ
  const int X = c & 7;               // [0,8)  over DIM
  const int row0 = Y * 128, col0 = X * 128;
  const int tid = threadIdx.x;

  // preamble: per-row global max/sum + chunk ratios (tid<128: one row each)
  if (tid < 128) {
    const int rg = row0 + tid;
    float m[16], s[16];
    const float4* pm = (const float4*)(AuxM + (size_t)rg * 16);
    const float4* ps = (const float4*)(AuxS + (size_t)rg * 16);
#pragma unroll
    for (int i = 0; i < 4; ++i) {
      float4 a = pm[i];
      m[4*i] = a.x; m[4*i+1] = a.y; m[4*i+2] = a.z; m[4*i+3] = a.w;
      float4 b = ps[i];
      s[4*i] = b.x; s[4*i+1] = b.y; s[4*i+2] = b.z; s[4*i+3] = b.w;
    }
    float gmax = m[0];
#pragma unroll
    for (int i = 1; i < 16; ++i) gmax = fmaxf(gmax, m[i]);
    float e[16];
    float gsum = 0.f;
#pragma unroll
    for (int i = 0; i < 16; ++i) { e[i] = __expf(m[i] - gmax); gsum += e[i] * s[i]; }
    const float inv = 1.f / gsum;
    float b[16];
#pragma unroll
    for (int i = 0; i < 16; ++i) b[i] = fmaxf(e[i] * inv, 1e-15f);
#pragma unroll
    for (int i = 1; i < 16; ++i) rt[tid][i] = b[i - 1] / b[i];
    rt[tid][0] = b[15];
  }
  __syncthreads();  // rt visible; drains preamble vmem -> vmcnt ledger clean

  const u16* A = P + (size_t)row0 * SEQ;
  const u16* B = VT + (size_t)col0 * SEQ;
  const int w = tid >> 6, l = tid & 63;
  const int wm = w >> 1, wn = w & 1;
  const int q = l >> 4, lr = l & 15;
  const int ao = wm * 2048 + l * 8;
  const int bo = wn * 2048 + l * 8;
  f32x4 acc[4][4];
#pragma unroll
  for (int mi = 0; mi < 4; ++mi)
#pragma unroll
    for (int ni = 0; ni < 4; ++ni)
      acc[mi][ni] = (f32x4){0.f, 0.f, 0.f, 0.f};

  stage_tile_pk(A, lds + 0 * 8192, tid);
  stage_tile_pk(B, lds + 0 * 8192 + 4096, tid);
  stage_tile_pk(A + 4096, lds + 1 * 8192, tid);
  stage_tile_pk(B + 4096, lds + 1 * 8192 + 4096, tid);
  stage_tile_pk(A + 8192, lds + 2 * 8192, tid);
  stage_tile_pk(B + 8192, lds + 2 * 8192 + 4096, tid);

  const int nkb = 128;
  for (int kb = 0; kb < nkb; ++kb) {
    if (kb && !(kb & 7)) {  // chunk transition: acc *= beta_{c-1}/beta_c
      const int ch = kb >> 3;
#pragma unroll
      for (int mi = 0; mi < 4; ++mi)
#pragma unroll
        for (int rr = 0; rr < 4; ++rr) {
          const float R = rt[wm * 64 + mi * 16 + q * 4 + rr][ch];
#pragma unroll
          for (int ni = 0; ni < 4; ++ni) acc[mi][ni][rr] *= R;
        }
    }
    if (kb + 2 < nkb) { VM8; } else if (kb + 1 < nkb) { VM4; } else { VM0; }
    BAR;
    if (kb + 3 < nkb) {
      u16* nb = lds + ((kb + 3) & 3) * 8192;
      const size_t off = (size_t)(kb + 3) * 4096;
      stage_tile_pk(A + off, nb, tid);
      stage_tile_pk(B + off, nb + 4096, tid);
    }
    const u16* cb = lds + (kb & 3) * 8192;
    bf16x8 av[4], bv[4];
#pragma unroll
    for (int i = 0; i < 4; ++i) {
      av[i] = *(const bf16x8*)(cb + ao + i * 512);
      bv[i] = *(const bf16x8*)(cb + 4096 + bo + i * 512);
    }
    __builtin_amdgcn_s_setprio(1);
#pragma unroll
    for (int mi = 0; mi < 4; ++mi)
#pragma unroll
      for (int ni = 0; ni < 4; ++ni)
        acc[mi][ni] = __builtin_amdgcn_mfma_f32_16x16x32_bf16(
            av[mi], bv[ni], acc[mi][ni], 0, 0, 0);
    __builtin_amdgcn_s_setprio(0);
  }

  // final scale + store
#pragma unroll
  for (int mi = 0; mi < 4; ++mi)
#pragma unroll
    for (int rr = 0; rr < 4; ++rr) {
      const int rloc = wm * 64 + mi * 16 + q * 4 + rr;
      const float F = rt[rloc][0];
      const int row = row0 + rloc;
#pragma unroll
      for (int ni = 0; ni < 4; ++ni) {
        const int col = col0 + wn * 64 + ni * 16 + lr;
        O[(size_t)row * DIM + col] = acc[mi][ni][rr] * F;
      }
    }
}

// ---------- launch ----------
extern "C" void kernel_launch(void* const* d_in, const int* in_sizes, int n_in,
                              void* d_out, int out_size, void* d_ws, size_t ws_size,
                              hipStream_t stream) {
  const float* X = (const float*)d_in[0];
  const float* Wq = (const float*)d_in[1];
  const float* Wk = (const float*)d_in[2];
  const float* Wv = (const float*)d_in[3];

  const size_t MB = 1024 * 1024;
  char* w = (char*)d_ws;
  u16* Xh = (u16*)(w + 0 * MB);    // 8 MB
  u16* Xl = (u16*)(w + 8 * MB);    // 8 MB
  u16* WqhT = (u16*)(w + 16 * MB); // 2 MB each
  u16* WqlT = (u16*)(w + 18 * MB);
  u16* WkhT = (u16*)(w + 20 * MB);
  u16* WklT = (u16*)(w + 22 * MB);
  u16* WvhT = (u16*)(w + 24 * MB);
  u16* Qh = (u16*)(w + 26 * MB);   // 8 MB each
  u16* Ql = (u16*)(w + 34 * MB);
  u16* Kh = (u16*)(w + 42 * MB);
  u16* Kl = (u16*)(w + 50 * MB);
  u16* VT = (u16*)(w + 58 * MB);   // 8 MB
  u16* P = (u16*)(w + 66 * MB);    // 32 MB (must NOT alias Qh..Kl: s reads
                                   //  Q/K while writing P')
  float* AuxM = (float*)(w + 98 * MB);  // 256 KB
  float* AuxS = (float*)(w + 99 * MB);  // 256 KB
  // total: 100 MB

  prep_kernel<<<dim3(32, 32, 4), dim3(32, 8), 0, stream>>>(
      X, Wq, Wk, Wv, Xh, Xl, WqhT, WqlT, WkhT, WklT, WvhT);
  qkv_kernel<<<dim3(DIM / 256, SEQ / 256, 3), 512, 0, stream>>>(
      Xh, Xl, WqhT, WqlT, WkhT, WklT, WvhT, Qh, Ql, Kh, Kl, VT);
  s_kernel<<<dim3(SEQ / 256, SEQ / 256), 512, 0, stream>>>(
      Qh, Ql, Kh, Kl, P, AuxM, AuxS);
  o_kernel<<<dim3(DIM / 128, SEQ / 128), 256, 0, stream>>>(
      P, VT, AuxM, AuxS, (float*)d_out);
}

// Round 12
// 299.949 us; speedup vs baseline: 1.0515x; 1.0515x over previous
//
#include <hip/hip_runtime.h>

typedef unsigned short u16;
typedef __attribute__((ext_vector_type(8))) short bf16x8;
typedef __attribute__((ext_vector_type(4))) float f32x4;

#define SEQ 4096
#define DIM 1024

// ---------- bf16 helpers (OCP bf16 = top 16 bits of fp32, RNE) ----------
__device__ __forceinline__ u16 f2bf(float f) {
  unsigned u = __float_as_uint(f);
  return (u16)((u + 0x7fffu + ((u >> 16) & 1u)) >> 16);
}
__device__ __forceinline__ float bf2f(u16 h) {
  return __uint_as_float(((unsigned)h) << 16);
}

// ---------- async global->LDS, 16B per lane ----------
__device__ __forceinline__ void gload_lds16(const void* g, void* l) {
  __builtin_amdgcn_global_load_lds(
      (const __attribute__((address_space(1))) void*)g,
      (__attribute__((address_space(3))) void*)l, 16, 0, 0);
}

// counted-vmcnt discipline (T4): literals only, "memory" clobber fences compiler
#define VM0 asm volatile("s_waitcnt vmcnt(0)" ::: "memory")
#define VM4 asm volatile("s_waitcnt vmcnt(4)" ::: "memory")
#define VM8 asm volatile("s_waitcnt vmcnt(8)" ::: "memory")
#define BAR __builtin_amdgcn_s_barrier()

// ---------- tile-packed operand layout (r4/r7-verified: 0 bank conflicts) ----------
// Matrix [R][Kd] stored as 128x32 tiles; tile (rb,kb) at (rb*(Kd/32)+kb)*4096.
// Within tile, 16B slot s = ((r7>>4)<<6) | ((c5>>3)<<4) | (r7&15), elem = c5&7.
__device__ __forceinline__ size_t pkoff(int row, int col, int kd) {
  int tile = (row >> 7) * (kd >> 5) + (col >> 5);
  int r7 = row & 127, c5 = col & 31;
  int slot = ((r7 >> 4) << 6) | ((c5 >> 3) << 4) | (r7 & 15);
  return (size_t)tile * 4096 + (size_t)(slot * 8 + (c5 & 7));
}

// stage a 2-tile quarter (256 rows x 32 K) with 512 threads: 2 gloads/thread
__device__ __forceinline__ void stage_q512(const u16* __restrict__ g,
                                           int kb, int nkb, u16* ldsq, int tid) {
  const int w = tid >> 6;  // 0..7
  gload_lds16(g + (size_t)kb * 4096 + tid * 8, ldsq + w * 512);
  gload_lds16(g + ((size_t)nkb + kb) * 4096 + tid * 8, ldsq + 4096 + w * 512);
}

// ---------- 256^2-tile 3-pair NT GEMM core, counted-vmcnt, 2-barrier ----------
// r3/r4/r6/r8-verified; r10: read-ahead NULL; r11: fused-softmax epilogue
// REGRESSED (+23us tail: exp + dependent shfl chains + 4-pass barriers as a
// serial tail with 1 block/CU — wrong regime, catalog #23) -> s is back to
// fp32-S out + separate softmax. This template is PLATEAUED at ~87us for s
// (3 schedule variants within 86.4-88.2); floor 103GF/2075TF = 50us.
// 3-pair split is numerically REQUIRED (softmax logit std ~O(300)).
__device__ __forceinline__ void gemm3_256(
    const u16* __restrict__ A0, const u16* __restrict__ A1,
    const u16* __restrict__ B0, const u16* __restrict__ B1,
    int nkb, u16* lds, f32x4 (&acc)[8][4]) {
  const int tid = threadIdx.x;       // 0..511
  const int w = tid >> 6, l = tid & 63;
  const int wm = w >> 2, wn = w & 3;

#pragma unroll
  for (int mi = 0; mi < 8; ++mi)
#pragma unroll
    for (int ni = 0; ni < 4; ++ni)
      acc[mi][ni] = (f32x4){0.f, 0.f, 0.f, 0.f};

  // quarter bases within a 32768-u16 buffer
  const int QA0 = 0, QA1 = 8192, QB0 = 16384, QB1 = 24576;
  const int aoff = wm * 4096 + l * 8;                       // + mi*512
  const int boff = ((wn & 2) >> 1) * 4096 + (wn & 1) * 2048 + l * 8;  // + ni*512

  // prologue: step 0, strict quarter order A0,B0 | B1,A1 (8 gloads)
  stage_q512(A0, 0, nkb, lds + QA0, tid);
  stage_q512(B0, 0, nkb, lds + QB0, tid);
  stage_q512(B1, 0, nkb, lds + QB1, tid);
  stage_q512(A1, 0, nkb, lds + QA1, tid);

  for (int kb = 0; kb < nkb; ++kb) {
    u16* cur = lds + (kb & 1) * 32768;
    u16* nxt = lds + ((kb + 1) & 1) * 32768;
    const bool pf = (kb + 1 < nkb);
    bf16x8 a0[8], b0[4];

    // ---- entry: A0,B0 of kb valid for all waves
    VM4;
    BAR;
    if (pf) {
      stage_q512(A0, kb + 1, nkb, nxt + QA0, tid);
      stage_q512(B0, kb + 1, nkb, nxt + QB0, tid);
    }
#pragma unroll
    for (int i = 0; i < 8; ++i) a0[i] = *(const bf16x8*)(cur + QA0 + aoff + i * 512);
#pragma unroll
    for (int i = 0; i < 4; ++i) b0[i] = *(const bf16x8*)(cur + QB0 + boff + i * 512);
    __builtin_amdgcn_s_setprio(1);
#pragma unroll
    for (int mi = 0; mi < 8; ++mi)
#pragma unroll
      for (int ni = 0; ni < 4; ++ni)
        acc[mi][ni] = __builtin_amdgcn_mfma_f32_16x16x32_bf16(
            a0[mi], b0[ni], acc[mi][ni], 0, 0, 0);
    __builtin_amdgcn_s_setprio(0);

    // ---- mid: B1,A1 of kb valid for all waves; then P1+P2 barrier-free
    if (pf) { VM4; } else { VM0; }
    BAR;
    if (pf) {
      stage_q512(B1, kb + 1, nkb, nxt + QB1, tid);
      stage_q512(A1, kb + 1, nkb, nxt + QA1, tid);
    }
    {
      bf16x8 b1[4];
#pragma unroll
      for (int i = 0; i < 4; ++i) b1[i] = *(const bf16x8*)(cur + QB1 + boff + i * 512);
      __builtin_amdgcn_s_setprio(1);
#pragma unroll
      for (int mi = 0; mi < 8; ++mi)
#pragma unroll
        for (int ni = 0; ni < 4; ++ni)
          acc[mi][ni] = __builtin_amdgcn_mfma_f32_16x16x32_bf16(
              a0[mi], b1[ni], acc[mi][ni], 0, 0, 0);
      __builtin_amdgcn_s_setprio(0);
    }
    {
      bf16x8 a1[8];
#pragma unroll
      for (int i = 0; i < 8; ++i) a1[i] = *(const bf16x8*)(cur + QA1 + aoff + i * 512);
      __builtin_amdgcn_s_setprio(1);
#pragma unroll
      for (int mi = 0; mi < 8; ++mi)
#pragma unroll
        for (int ni = 0; ni < 4; ++ni)
          acc[mi][ni] = __builtin_amdgcn_mfma_f32_16x16x32_bf16(
              a1[mi], b0[ni], acc[mi][ni], 0, 0, 0);
      __builtin_amdgcn_s_setprio(0);
    }
  }
  __syncthreads();
}

// ---------- 256^2-tile single-pair NT GEMM core, counted-vmcnt ----------
// HW-VERIFIED (r4, qkv z=2). 4 rotating 32KB bufs, depth-3 prefetch,
// vmcnt(8) steady / 4 / 0 tail.
__device__ __forceinline__ void gemm1_256(
    const u16* __restrict__ A, const u16* __restrict__ B,
    int nkb, u16* lds, f32x4 (&acc)[8][4]) {
  const int tid = threadIdx.x;
  const int w = tid >> 6, l = tid & 63;
  const int wm = w >> 2, wn = w & 3;

#pragma unroll
  for (int mi = 0; mi < 8; ++mi)
#pragma unroll
    for (int ni = 0; ni < 4; ++ni)
      acc[mi][ni] = (f32x4){0.f, 0.f, 0.f, 0.f};

  const int aoff = wm * 4096 + l * 8;
  const int boff = ((wn & 2) >> 1) * 4096 + (wn & 1) * 2048 + l * 8;

  stage_q512(A, 0, nkb, lds + 0 * 16384, tid);
  stage_q512(B, 0, nkb, lds + 0 * 16384 + 8192, tid);
  stage_q512(A, 1, nkb, lds + 1 * 16384, tid);
  stage_q512(B, 1, nkb, lds + 1 * 16384 + 8192, tid);
  stage_q512(A, 2, nkb, lds + 2 * 16384, tid);
  stage_q512(B, 2, nkb, lds + 2 * 16384 + 8192, tid);

  for (int kb = 0; kb < nkb; ++kb) {
    if (kb + 2 < nkb) { VM8; } else if (kb + 1 < nkb) { VM4; } else { VM0; }
    BAR;
    if (kb + 3 < nkb) {
      u16* nb = lds + ((kb + 3) & 3) * 16384;
      stage_q512(A, kb + 3, nkb, nb, tid);
      stage_q512(B, kb + 3, nkb, nb + 8192, tid);
    }
    const u16* cb = lds + (kb & 3) * 16384;
    bf16x8 av[8], bv[4];
#pragma unroll
    for (int i = 0; i < 8; ++i) av[i] = *(const bf16x8*)(cb + aoff + i * 512);
#pragma unroll
    for (int i = 0; i < 4; ++i) bv[i] = *(const bf16x8*)(cb + 8192 + boff + i * 512);
    __builtin_amdgcn_s_setprio(1);
#pragma unroll
    for (int mi = 0; mi < 8; ++mi)
#pragma unroll
      for (int ni = 0; ni < 4; ++ni)
        acc[mi][ni] = __builtin_amdgcn_mfma_f32_16x16x32_bf16(
            av[mi], bv[ni], acc[mi][ni], 0, 0, 0);
    __builtin_amdgcn_s_setprio(0);
  }
  __syncthreads();
}

// C/D layout (m89/m91 verified): lane l, reg r -> row=(l>>4)*4+r, col=l&15
#define EPILOGUE_IDX                                          \
  const int tid = threadIdx.x, w = tid >> 6, l = tid & 63;    \
  const int wm = w >> 1, wn = w & 1, lr = l & 15, q = l >> 4; \
  (void)tid;

// ---------- 512-thr epilogue: 256^2 C regs -> packed bf16 h/l via LDS ----------
// template<HASL> specialization (r8): no runtime if(L) in the VT instantiation.
template <bool HASL>
__device__ __forceinline__ void epilogue_pack256(
    f32x4 (&acc)[8][4], u16* lds, int row0, int col0, int kd,
    u16* __restrict__ H, u16* __restrict__ L) {
  const int tid = threadIdx.x, w = tid >> 6, l = tid & 63;
  const int wm = w >> 2, wn = w & 3, lr = l & 15, q = l >> 4;
  float* lC = (float*)lds;
#pragma unroll
  for (int p = 0; p < 4; ++p) {
    if (wm == (p >> 1)) {
      const int mib = (p & 1) * 4;
#pragma unroll
      for (int mi2 = 0; mi2 < 4; ++mi2)
#pragma unroll
        for (int ni = 0; ni < 4; ++ni)
#pragma unroll
          for (int r = 0; r < 4; ++r)
            lC[(mi2 * 16 + q * 4 + r) * 260 + wn * 64 + ni * 16 + lr] =
                acc[mib + mi2][ni][r];
    }
    __syncthreads();
#pragma unroll
    for (int j = 0; j < 2; ++j) {
      int u = tid + 512 * j;
      int row = u >> 4, c0 = (u & 15) * 16;
      u16 hbuf[16], lbuf[16];
#pragma unroll
      for (int i = 0; i < 16; ++i) {
        float v = lC[row * 260 + c0 + i];
        u16 hv = f2bf(v);
        hbuf[i] = hv;
        if (HASL) lbuf[i] = f2bf(v - bf2f(hv));
      }
      int rg = row0 + p * 64 + row;
      size_t o0 = pkoff(rg, col0 + c0, kd);
      size_t o1 = pkoff(rg, col0 + c0 + 8, kd);
      *(bf16x8*)(H + o0) = *(bf16x8*)(hbuf);
      *(bf16x8*)(H + o1) = *(bf16x8*)(hbuf + 8);
      if (HASL) {
        *(bf16x8*)(L + o0) = *(bf16x8*)(lbuf);
        *(bf16x8*)(L + o1) = *(bf16x8*)(lbuf + 8);
      }
    }
    if (p < 3) __syncthreads();
  }
}

// ---------- kernels ----------

__global__ __launch_bounds__(256) void prep_kernel(
    const float* __restrict__ X,
    const float* __restrict__ W0, const float* __restrict__ W1, const float* __restrict__ W2,
    u16* __restrict__ Xh, u16* __restrict__ Xl,
    u16* __restrict__ H0, u16* __restrict__ L0,
    u16* __restrict__ H1, u16* __restrict__ L1,
    u16* __restrict__ H2) {
  const int z = blockIdx.z;
  const int tx = threadIdx.x, ty = threadIdx.y;
  if (z == 0) {
    int idx = (blockIdx.y * 32 + blockIdx.x) * 256 + ty * 32 + tx;
    int row = idx >> 6;
    int c0 = (idx & 63) * 16;
    u16 h[16], lo[16];
#pragma unroll
    for (int j = 0; j < 4; ++j) {
      float4 x = *(const float4*)(X + (size_t)row * DIM + c0 + j * 4);
      float v;
      v = x.x; h[j*4+0] = f2bf(v); lo[j*4+0] = f2bf(v - bf2f(h[j*4+0]));
      v = x.y; h[j*4+1] = f2bf(v); lo[j*4+1] = f2bf(v - bf2f(h[j*4+1]));
      v = x.z; h[j*4+2] = f2bf(v); lo[j*4+2] = f2bf(v - bf2f(h[j*4+2]));
      v = x.w; h[j*4+3] = f2bf(v); lo[j*4+3] = f2bf(v - bf2f(h[j*4+3]));
    }
    size_t o0 = pkoff(row, c0, DIM);
    size_t o1 = pkoff(row, c0 + 8, DIM);
    *(bf16x8*)(Xh + o0) = *(bf16x8*)(h);
    *(bf16x8*)(Xl + o0) = *(bf16x8*)(lo);
    *(bf16x8*)(Xh + o1) = *(bf16x8*)(h + 8);
    *(bf16x8*)(Xl + o1) = *(bf16x8*)(lo + 8);
    return;
  }
  __shared__ float t[32][33];
  const float* W = (z == 1) ? W0 : (z == 2) ? W1 : W2;
  u16* H = (z == 1) ? H0 : (z == 2) ? H1 : H2;
  u16* L = (z == 1) ? L0 : (z == 2) ? L1 : nullptr;
  const int i0 = blockIdx.y * 32, o0 = blockIdx.x * 32;
#pragma unroll
  for (int m = 0; m < 4; ++m)
    t[ty + 8 * m][tx] = W[(size_t)(i0 + ty + 8 * m) * DIM + o0 + tx];
  __syncthreads();
#pragma unroll
  for (int m = 0; m < 4; ++m) {
    float v = t[tx][ty + 8 * m];
    u16 h = f2bf(v);
    size_t o = pkoff(o0 + ty + 8 * m, i0 + tx, DIM);
    H[o] = h;
    if (L) L[o] = f2bf(v - bf2f(h));
  }
}

// qkv on the 256^2 counted-vmcnt cores. Grid 4x16x3, 512 thr, T1 swizzle.
__global__ __launch_bounds__(512, 2) void qkv_kernel(
    const u16* __restrict__ Xh, const u16* __restrict__ Xl,
    const u16* __restrict__ Wh0, const u16* __restrict__ Wl0,
    const u16* __restrict__ Wh1, const u16* __restrict__ Wl1,
    const u16* __restrict__ Wh2,
    u16* __restrict__ Qh, u16* __restrict__ Ql,
    u16* __restrict__ Kh, u16* __restrict__ Kl,
    u16* __restrict__ VT) {
  __shared__ __align__(16) u16 lds[2 * 32768];  // 128 KB
  const int z = blockIdx.z;
  const int bid = blockIdx.y * 4 + blockIdx.x;  // [0,64)
  const int xcd = bid & 7, c = bid >> 3;        // c in [0,8)
  const int Y = xcd * 2 + (c >> 2);             // [0,16) over SEQ panels
  const int Xp = c & 3;                         // [0,4)  over DIM panels
  f32x4 acc[8][4];
  if (z < 2) {
    const u16* Wh = z ? Wh1 : Wh0;
    const u16* Wl = z ? Wl1 : Wl0;
    const int row0 = Y * 256;   // over SEQ
    const int col0 = Xp * 256;  // over DIM
    gemm3_256(Xh + (size_t)row0 * DIM, Xl + (size_t)row0 * DIM,
              Wh + (size_t)col0 * DIM, Wl + (size_t)col0 * DIM,
              DIM / 32, lds, acc);
    epilogue_pack256<true>(acc, lds, row0, col0, DIM, z ? Kh : Qh, z ? Kl : Ql);
  } else {
    const int row0 = Xp * 256;  // over DIM
    const int col0 = Y * 256;   // over SEQ
    gemm1_256(Wh2 + (size_t)row0 * DIM, Xh + (size_t)col0 * DIM,
              DIM / 32, lds, acc);
    epilogue_pack256<false>(acc, lds, row0, col0, SEQ, VT, nullptr);
  }
}

// S = (Q K^T) * 1/32, split-precision fused 3-pair, fp32 row-major out.
// 256^2 tile, 512 thr, counted-vmcnt 2-barrier pipeline (r8 body restored).
__global__ __launch_bounds__(512, 2) void s_kernel(
    const u16* __restrict__ Qh, const u16* __restrict__ Ql,
    const u16* __restrict__ Kh, const u16* __restrict__ Kl,
    float* __restrict__ S) {
  __shared__ __align__(16) u16 lds[2 * 32768];  // 128 KB
  const int bid = blockIdx.y * 16 + blockIdx.x;  // [0,256)
  const int xcd = bid & 7, c = bid >> 3;         // c in [0,32)
  const int Y = (xcd & 3) * 4 + (c >> 3);        // [0,16)
  const int X = (xcd >> 2) * 8 + (c & 7);        // [0,16)
  const int row0 = Y * 256, col0 = X * 256;
  f32x4 acc[8][4];
  gemm3_256(Qh + (size_t)row0 * DIM, Ql + (size_t)row0 * DIM,
            Kh + (size_t)col0 * DIM, Kl + (size_t)col0 * DIM,
            DIM / 32, lds, acc);
  const int tid = threadIdx.x, w = tid >> 6, l = tid & 63;
  const int wm = w >> 2, wn = w & 3, lr = l & 15, q = l >> 4;
  const float scale = 0.03125f;  // 1/sqrt(1024)
#pragma unroll
  for (int mi = 0; mi < 8; ++mi)
#pragma unroll
    for (int ni = 0; ni < 4; ++ni)
#pragma unroll
      for (int r = 0; r < 4; ++r) {
        int row = row0 + wm * 128 + mi * 16 + q * 4 + r;
        int col = col0 + wn * 64 + ni * 16 + lr;
        S[(size_t)row * SEQ + col] = acc[mi][ni][r] * scale;
      }
}

// row softmax: S fp32 [4096][4096] -> P bf16 tile-packed (Kd=SEQ)
__global__ __launch_bounds__(256) void softmax_kernel(const float* __restrict__ S,
                                                      u16* __restrict__ P) {
  const int row = blockIdx.x;
  const float* s = S + (size_t)row * SEQ;
  const int tid = threadIdx.x;
  const int c0 = tid * 16;
  float v[16];
  float mx = -3.4e38f;
#pragma unroll
  for (int j = 0; j < 4; ++j) {
    float4 x = *(const float4*)(s + c0 + j * 4);
    v[j * 4 + 0] = x.x; v[j * 4 + 1] = x.y; v[j * 4 + 2] = x.z; v[j * 4 + 3] = x.w;
    mx = fmaxf(mx, fmaxf(fmaxf(x.x, x.y), fmaxf(x.z, x.w)));
  }
#pragma unroll
  for (int off = 32; off; off >>= 1) mx = fmaxf(mx, __shfl_xor(mx, off));
  __shared__ float red[8];
  const int w = tid >> 6, l = tid & 63;
  if (l == 0) red[w] = mx;
  __syncthreads();
  mx = fmaxf(fmaxf(red[0], red[1]), fmaxf(red[2], red[3]));
  float sum = 0.f;
#pragma unroll
  for (int i = 0; i < 16; ++i) {
    v[i] = __expf(v[i] - mx);
    sum += v[i];
  }
#pragma unroll
  for (int off = 32; off; off >>= 1) sum += __shfl_xor(sum, off);
  if (l == 0) red[4 + w] = sum;
  __syncthreads();
  sum = red[4] + red[5] + red[6] + red[7];
  const float inv = 1.f / sum;
  u16 p[16];
#pragma unroll
  for (int i = 0; i < 16; ++i) p[i] = f2bf(v[i] * inv);
  *(bf16x8*)(P + pkoff(row, c0, SEQ)) = *(bf16x8*)(p);
  *(bf16x8*)(P + pkoff(row, c0 + 8, SEQ)) = *(bf16x8*)(p + 8);
}

// ---------- o-only code at module end (r8 codegen isolation) ----------

// stage one packed 128x32 tile (4096 elems, contiguous) into LDS (256 thr)
__device__ __forceinline__ void stage_tile_pk(const u16* __restrict__ g,
                                              u16* lds, int tid) {
  const int w = tid >> 6;
  gload_lds16(g + (size_t)tid * 8, lds + (size_t)(w * 64) * 8);
  gload_lds16(g + (size_t)(256 + tid) * 8, lds + (size_t)(256 + w * 64) * 8);
}

// 128^2-tile single-pair NT GEMM core, counted-vmcnt (r7-verified in o).
__device__ __forceinline__ void gemm1_ctd128(
    const u16* __restrict__ A, const u16* __restrict__ B,
    int nkb, u16* lds, f32x4 (&acc)[4][4]) {
  const int tid = threadIdx.x;
  const int w = tid >> 6, l = tid & 63;
  const int wm = w >> 1, wn = w & 1;

#pragma unroll
  for (int mi = 0; mi < 4; ++mi)
#pragma unroll
    for (int ni = 0; ni < 4; ++ni)
      acc[mi][ni] = (f32x4){0.f, 0.f, 0.f, 0.f};

  const int ao = wm * 2048 + l * 8;
  const int bo = wn * 2048 + l * 8;

  stage_tile_pk(A, lds + 0 * 8192, tid);
  stage_tile_pk(B, lds + 0 * 8192 + 4096, tid);
  stage_tile_pk(A + 4096, lds + 1 * 8192, tid);
  stage_tile_pk(B + 4096, lds + 1 * 8192 + 4096, tid);
  stage_tile_pk(A + 8192, lds + 2 * 8192, tid);
  stage_tile_pk(B + 8192, lds + 2 * 8192 + 4096, tid);

  for (int kb = 0; kb < nkb; ++kb) {
    if (kb + 2 < nkb) { VM8; } else if (kb + 1 < nkb) { VM4; } else { VM0; }
    BAR;
    if (kb + 3 < nkb) {
      u16* nb = lds + ((kb + 3) & 3) * 8192;
      const size_t off = (size_t)(kb + 3) * 4096;
      stage_tile_pk(A + off, nb, tid);
      stage_tile_pk(B + off, nb + 4096, tid);
    }
    const u16* cb = lds + (kb & 3) * 8192;
    bf16x8 av[4], bv[4];
#pragma unroll
    for (int i = 0; i < 4; ++i) {
      av[i] = *(const bf16x8*)(cb + ao + i * 512);
      bv[i] = *(const bf16x8*)(cb + 4096 + bo + i * 512);
    }
    __builtin_amdgcn_s_setprio(1);
#pragma unroll
    for (int mi = 0; mi < 4; ++mi)
#pragma unroll
      for (int ni = 0; ni < 4; ++ni)
        acc[mi][ni] = __builtin_amdgcn_mfma_f32_16x16x32_bf16(
            av[mi], bv[ni], acc[mi][ni], 0, 0, 0);
    __builtin_amdgcn_s_setprio(0);
  }
  __syncthreads();
}

// O partial = P[:, z*2048:(z+1)*2048] @ V[...] — r12: split-K=2 RESTORED.
// r5's de-split silently halved o residency (1 block/CU = 1 wave/SIMD, zero
// latency hiding). 512 blocks, 64KB LDS -> 2 blocks/CU = 2 waves/SIMD.
__global__ __launch_bounds__(256, 2) void o_kernel(const u16* __restrict__ P,
                                                   const u16* __restrict__ VT,
                                                   float* __restrict__ Opart) {
  __shared__ __align__(16) u16 lds[4 * 8192];  // 64 KB
  const int z = blockIdx.z;
  const int bid = blockIdx.y * 8 + blockIdx.x;  // [0,256)
  const int xcd = bid & 7, c = bid >> 3;
  const int Y = xcd * 4 + (c >> 3);  // [0,32) over SEQ
  const int X = c & 7;               // [0,8)  over DIM
  const int row0 = Y * 128, col0 = X * 128;
  const u16* A = P + (size_t)row0 * SEQ + (size_t)z * 64 * 4096;
  const u16* B = VT + (size_t)col0 * SEQ + (size_t)z * 64 * 4096;
  f32x4 acc[4][4];
  gemm1_ctd128(A, B, 64, lds, acc);
  EPILOGUE_IDX
  float* O = Opart + (size_t)z * SEQ * DIM;
#pragma unroll
  for (int mi = 0; mi < 4; ++mi)
#pragma unroll
    for (int ni = 0; ni < 4; ++ni)
#pragma unroll
      for (int r = 0; r < 4; ++r) {
        int row = row0 + wm * 64 + mi * 16 + q * 4 + r;
        int col = col0 + wn * 64 + ni * 16 + lr;
        O[(size_t)row * DIM + col] = acc[mi][ni][r];
      }
}

__global__ __launch_bounds__(256) void o_reduce_kernel(const float* __restrict__ Op,
                                                       float* __restrict__ O) {
  const size_t N = (size_t)SEQ * DIM;
  size_t i = ((size_t)blockIdx.x * 256 + threadIdx.x) * 4;
  float4 a = *(const float4*)(Op + i);
  float4 b = *(const float4*)(Op + N + i);
  float4 rr;
  rr.x = a.x + b.x;
  rr.y = a.y + b.y;
  rr.z = a.z + b.z;
  rr.w = a.w + b.w;
  *(float4*)(O + i) = rr;
}

// ---------- launch ----------
extern "C" void kernel_launch(void* const* d_in, const int* in_sizes, int n_in,
                              void* d_out, int out_size, void* d_ws, size_t ws_size,
                              hipStream_t stream) {
  const float* X = (const float*)d_in[0];
  const float* Wq = (const float*)d_in[1];
  const float* Wk = (const float*)d_in[2];
  const float* Wv = (const float*)d_in[3];

  const size_t MB = 1024 * 1024;
  char* w = (char*)d_ws;
  u16* Xh = (u16*)(w + 0 * MB);    // 8 MB
  u16* Xl = (u16*)(w + 8 * MB);    // 8 MB
  u16* WqhT = (u16*)(w + 16 * MB); // 2 MB each
  u16* WqlT = (u16*)(w + 18 * MB);
  u16* WkhT = (u16*)(w + 20 * MB);
  u16* WklT = (u16*)(w + 22 * MB);
  u16* WvhT = (u16*)(w + 24 * MB);
  u16* Qh = (u16*)(w + 26 * MB);   // 8 MB each
  u16* Ql = (u16*)(w + 34 * MB);
  u16* Kh = (u16*)(w + 42 * MB);
  u16* Kl = (u16*)(w + 50 * MB);
  u16* VT = (u16*)(w + 58 * MB);   // 8 MB
  float* S = (float*)(w + 66 * MB);    // 64 MB
  u16* P = (u16*)(w + 26 * MB);        // aliases Qh..Kl (dead after s_kernel)
  float* Opart = (float*)(w + 66 * MB);// aliases S (dead after softmax), 32 MB
  // total: 130 MB

  prep_kernel<<<dim3(32, 32, 4), dim3(32, 8), 0, stream>>>(
      X, Wq, Wk, Wv, Xh, Xl, WqhT, WqlT, WkhT, WklT, WvhT);
  qkv_kernel<<<dim3(DIM / 256, SEQ / 256, 3), 512, 0, stream>>>(
      Xh, Xl, WqhT, WqlT, WkhT, WklT, WvhT, Qh, Ql, Kh, Kl, VT);
  s_kernel<<<dim3(SEQ / 256, SEQ / 256), 512, 0, stream>>>(Qh, Ql, Kh, Kl, S);
  softmax_kernel<<<SEQ, 256, 0, stream>>>(S, P);
  o_kernel<<<dim3(DIM / 128, SEQ / 128, 2), 256, 0, stream>>>(P, VT, Opart);
  o_reduce_kernel<<<(SEQ * DIM) / (256 * 4), 256, 0, stream>>>(Opart, (float*)d_out);
}